// Round 1
// baseline (205.623 us; speedup 1.0000x reference)
//
#include <hip/hip_runtime.h>
#include <hip/hip_cooperative_groups.h>

namespace cg = cooperative_groups;

#define NN 10000
#define KK 64
#define CC 128
#define OUTOFF (NN * CC)
#define NA 256        // grid size == split-K blocks
#define CHUNKS_A 625  // 625 * 16 == 10000

__device__ __forceinline__ float4 f4fma(float s, float4 v, float4 a) {
    a.x = fmaf(s, v.x, a.x); a.y = fmaf(s, v.y, a.y);
    a.z = fmaf(s, v.z, a.z); a.w = fmaf(s, v.w, a.w);
    return a;
}
__device__ __forceinline__ float4 f4add(float4 a, float4 b) {
    a.x += b.x; a.y += b.y; a.z += b.z; a.w += b.w; return a;
}

// ws layout (floats): [0 .. NA*16384)  partials [b][m][k][c]   (16.8 MB)
//                     [NA*16384 .. +16384)  UVW [m][k][c]      (64 KB)

__global__ __launch_bounds__(512) void kFused(
        const float* __restrict__ re, const float* __restrict__ im,
        const float* __restrict__ Qr, const float* __restrict__ Qi,
        const float* __restrict__ Ritz, const float* __restrict__ W,
        const int* __restrict__ ldp,
        float* __restrict__ out, float* __restrict__ ws)
{
    __shared__ float4 smem[1536];   // 24 KB, reused across phases
    cg::grid_group grid = cg::this_grid();
    const int t = threadIdx.x;
    const int bid = blockIdx.x;
    float* part = ws;
    float* UVW  = ws + (size_t)NA * 16384;

    // ---------------- Phase 1: partial U,V = split-K of Q^H X ----------------
    {
        const int kt = t & 15;        // k0 = 4*kt
        const int ctA = t >> 4;       // c0 = 4*ctA (0..31)
        const int row_q = (t & 255) >> 4, q_q = t & 15;
        const int row_x = t >> 5,          q_x = t & 31;
        const float4* gq  = (const float4*)((t < 256) ? Qr : Qi);  // wave-uniform
        const float4* gre = (const float4*)re;
        const float4* gim = (const float4*)im;

        float aU[4][4] = {}, aV[4][4] = {};
        int cb = bid;
        float4 r0 = gq [(size_t)(cb * 16 + row_q) * 16 + q_q];
        float4 r1 = gre[(size_t)(cb * 16 + row_x) * 32 + q_x];
        float4 r2 = gim[(size_t)(cb * 16 + row_x) * 32 + q_x];

        while (true) {
            smem[t] = r0; smem[512 + t] = r1; smem[1024 + t] = r2;
            __syncthreads();
            const int nx = cb + NA;
            if (nx < CHUNKS_A) {   // register prefetch of next chunk
                const int m0 = nx * 16;
                r0 = gq [(size_t)(m0 + row_q) * 16 + q_q];
                r1 = gre[(size_t)(m0 + row_x) * 32 + q_x];
                r2 = gim[(size_t)(m0 + row_x) * 32 + q_x];
            }
#pragma unroll 4
            for (int rr = 0; rr < 16; ++rr) {
                float4 q_r = smem[rr * 16 + kt];
                float4 q_i = smem[256 + rr * 16 + kt];
                float4 x_r = smem[512 + rr * 32 + ctA];
                float4 x_i = smem[1024 + rr * 32 + ctA];
                float qr_[4] = {q_r.x, q_r.y, q_r.z, q_r.w};
                float qi_[4] = {q_i.x, q_i.y, q_i.z, q_i.w};
                float xr_[4] = {x_r.x, x_r.y, x_r.z, x_r.w};
                float xi_[4] = {x_i.x, x_i.y, x_i.z, x_i.w};
#pragma unroll
                for (int a = 0; a < 4; ++a)
#pragma unroll
                    for (int b = 0; b < 4; ++b) {
                        aU[a][b] = fmaf(qr_[a], xr_[b], aU[a][b]);
                        aU[a][b] = fmaf(qi_[a], xi_[b], aU[a][b]);
                        aV[a][b] = fmaf(qi_[a], xr_[b], aV[a][b]);
                        aV[a][b] = fmaf(-qr_[a], xi_[b], aV[a][b]);
                    }
            }
            __syncthreads();
            if (nx >= CHUNKS_A) break;
            cb = nx;
        }
        float* base = part + (size_t)bid * 16384;
        const int k0 = kt * 4, c0 = ctA * 4;
#pragma unroll
        for (int a = 0; a < 4; ++a) {
            *(float4*)(base + (k0 + a) * CC + c0)        = make_float4(aU[a][0], aU[a][1], aU[a][2], aU[a][3]);
            *(float4*)(base + 8192 + (k0 + a) * CC + c0) = make_float4(aV[a][0], aV[a][1], aV[a][2], aV[a][3]);
        }
    }

    grid.sync();

    // ---------------- Phase 2: reduce 256 partials -> UVW = TT * row @ W ----------------
    // 128 active blocks = (m in {U,V}) x (k in 0..63); 512 threads, 16 loads each
    if (bid < 128) {
        float4* red4 = smem;                       // 512 float4
        float*  rowS = (float*)(smem + 512);       // 128 floats
        const int m = bid >> 6, k = bid & 63;
        const int q = t & 31, sl = t >> 5;         // sl: 0..15
        const float4* p = (const float4*)part + (size_t)sl * 4096 + m * 2048 + k * 32 + q;
        float4 z = make_float4(0.f, 0.f, 0.f, 0.f);
        float4 s0 = z, s1 = z, s2 = z, s3 = z;
#pragma unroll
        for (int i = 0; i < 4; ++i) {              // b = sl + 16*i  (stride 16*4096 f4)
            s0 = f4add(s0, p[(size_t)(i)      * 65536]);
            s1 = f4add(s1, p[(size_t)(i + 4)  * 65536]);
            s2 = f4add(s2, p[(size_t)(i + 8)  * 65536]);
            s3 = f4add(s3, p[(size_t)(i + 12) * 65536]);
        }
        red4[t] = f4add(f4add(s0, s1), f4add(s2, s3));
        __syncthreads();
        if (t < 32) {
            float4 tot = z;
#pragma unroll
            for (int g = 0; g < 16; ++g) tot = f4add(tot, red4[g * 32 + t]);
            ((float4*)rowS)[t] = tot;
        }
        __syncthreads();
        if (t < 128) {
            float acc = 0.f;
#pragma unroll 8
            for (int cp = 0; cp < 128; ++cp)
                acc = fmaf(rowS[cp], W[cp * 128 + t], acc);
            const int ld = *ldp;
            const float rz = Ritz[k];
            float tt = 1.f;
            for (int i = 0; i < ld; ++i) tt *= rz;
            UVW[m * 8192 + k * 128 + t] = tt * acc;
        }
    }

    grid.sync();

    // ---------------- Phase 3: res = Q @ UVW + masked-ReLU epilogue ----------------
    // grid-stride over 625 16-row tiles; 512 threads = 16 rows x 32 col-f4-groups.
    // UVW (64 KB) read directly from global: coalesced 512 B/wave-inst, L1/L2-hot.
    {
        const float4* U4 = (const float4*)UVW;     // [64][32]
        const float4* V4 = U4 + 2048;
        const int ct = t & 31;                     // cols 4*ct..+3
        const int r  = t >> 5;                     // 0..15
        const float4 z = make_float4(0.f, 0.f, 0.f, 0.f);
        for (int j = bid; j < CHUNKS_A; j += NA) {
            const int na = j * 16 + r;
            const float4* qr4 = (const float4*)(Qr + (size_t)na * KK);
            const float4* qi4 = (const float4*)(Qi + (size_t)na * KK);
            float4 Ra = z, Ia = z;
#pragma unroll 4
            for (int k4 = 0; k4 < 16; ++k4) {
                float4 QR = qr4[k4], QI = qi4[k4];
                float ar[4] = {QR.x, QR.y, QR.z, QR.w};
                float ai[4] = {QI.x, QI.y, QI.z, QI.w};
#pragma unroll
                for (int jj = 0; jj < 4; ++jj) {
                    const int k = k4 * 4 + jj;
                    float4 uw = U4[k * 32 + ct];
                    float4 vw = V4[k * 32 + ct];
                    Ra = f4fma(ar[jj], uw, Ra); Ra = f4fma(ai[jj], vw, Ra);
                    Ia = f4fma(ai[jj], uw, Ia); Ia = f4fma(-ar[jj], vw, Ia);
                }
            }
            const int cc = ct * 4;
            float4 rin = *(const float4*)(re + (size_t)na * CC + cc);
            float4 iin = *(const float4*)(im + (size_t)na * CC + cc);
            float4 orr, oii;
            orr.x = rin.x + (Ra.x >= 0.f ? Ra.x : 0.f); oii.x = iin.x + (Ra.x >= 0.f ? Ia.x : 0.f);
            orr.y = rin.y + (Ra.y >= 0.f ? Ra.y : 0.f); oii.y = iin.y + (Ra.y >= 0.f ? Ia.y : 0.f);
            orr.z = rin.z + (Ra.z >= 0.f ? Ra.z : 0.f); oii.z = iin.z + (Ra.z >= 0.f ? Ia.z : 0.f);
            orr.w = rin.w + (Ra.w >= 0.f ? Ra.w : 0.f); oii.w = iin.w + (Ra.w >= 0.f ? Ia.w : 0.f);
            *(float4*)(out + (size_t)na * CC + cc)          = orr;
            *(float4*)(out + OUTOFF + (size_t)na * CC + cc) = oii;
        }
    }
}

extern "C" void kernel_launch(void* const* d_in, const int* in_sizes, int n_in,
                              void* d_out, int out_size, void* d_ws, size_t ws_size,
                              hipStream_t stream) {
    const float* re   = (const float*)d_in[0];
    const float* im   = (const float*)d_in[1];
    const float* Qr   = (const float*)d_in[2];
    const float* Qi   = (const float*)d_in[3];
    const float* Ritz = (const float*)d_in[4];
    const float* W    = (const float*)d_in[5];
    const int*   ldp  = (const int*)d_in[6];
    float* out = (float*)d_out;
    float* ws  = (float*)d_ws;

    void* args[] = {(void*)&re, (void*)&im, (void*)&Qr, (void*)&Qi,
                    (void*)&Ritz, (void*)&W, (void*)&ldp, (void*)&out, (void*)&ws};
    hipLaunchCooperativeKernel((const void*)kFused, dim3(NA), dim3(512), args, 0, stream);
}

// Round 2
// 123.087 us; speedup vs baseline: 1.6706x; 1.6706x over previous
//
#include <hip/hip_runtime.h>

#define NN 10000
#define KK 64
#define CC 128
#define OUTOFF (NN * CC)
#define NCH 625            // 16-row chunks; 625*16 == 10000; also split-K count
#define PART_F4 4096       // float4 per partial tile (16384 floats = [2][64][32] f4)

__device__ __forceinline__ float4 f4fma(float s, float4 v, float4 a) {
    a.x = fmaf(s, v.x, a.x); a.y = fmaf(s, v.y, a.y);
    a.z = fmaf(s, v.z, a.z); a.w = fmaf(s, v.w, a.w);
    return a;
}
__device__ __forceinline__ float4 f4add(float4 a, float4 b) {
    a.x += b.x; a.y += b.y; a.z += b.z; a.w += b.w; return a;
}

// ws layout (floats): [0 .. 625*16384)        partials [b][m][k][c]  (41 MB)
//                     [+0 .. +16384)           row  [m][k][c]
//                     [+16384 .. +32768)       UVW  [m][k][c]

// ---------------- kA: one 16-row chunk per block -> partial U,V ----------------
// 625 blocks x 512 threads (4x4 register tile over 64k x 128c)
__global__ __launch_bounds__(512) void kA(const float* __restrict__ re,
                                          const float* __restrict__ im,
                                          const float* __restrict__ Qr,
                                          const float* __restrict__ Qi,
                                          float* __restrict__ part)
{
    __shared__ float4 smem[1536];   // Qr 256 | Qi 256 | re 512 | im 512
    const int t = threadIdx.x;
    const int bid = blockIdx.x;     // chunk index == split-K index
    const int kt = t & 15;          // k0 = 4*kt
    const int ctA = t >> 4;         // c0 = 4*ctA (0..31)
    const int row_q = (t & 255) >> 4, q_q = t & 15;
    const int row_x = t >> 5,          q_x = t & 31;
    const float4* gq  = (const float4*)((t < 256) ? Qr : Qi);   // wave-uniform
    const float4* gre = (const float4*)re;
    const float4* gim = (const float4*)im;

    smem[t]        = gq [(size_t)(bid * 16 + row_q) * 16 + q_q];
    smem[512 + t]  = gre[(size_t)(bid * 16 + row_x) * 32 + q_x];
    smem[1024 + t] = gim[(size_t)(bid * 16 + row_x) * 32 + q_x];
    __syncthreads();

    float aU[4][4] = {}, aV[4][4] = {};
#pragma unroll 4
    for (int rr = 0; rr < 16; ++rr) {
        float4 q_r = smem[rr * 16 + kt];
        float4 q_i = smem[256 + rr * 16 + kt];
        float4 x_r = smem[512 + rr * 32 + ctA];
        float4 x_i = smem[1024 + rr * 32 + ctA];
        float qr_[4] = {q_r.x, q_r.y, q_r.z, q_r.w};
        float qi_[4] = {q_i.x, q_i.y, q_i.z, q_i.w};
        float xr_[4] = {x_r.x, x_r.y, x_r.z, x_r.w};
        float xi_[4] = {x_i.x, x_i.y, x_i.z, x_i.w};
#pragma unroll
        for (int a = 0; a < 4; ++a)
#pragma unroll
            for (int b = 0; b < 4; ++b) {
                aU[a][b] = fmaf(qr_[a], xr_[b], aU[a][b]);
                aU[a][b] = fmaf(qi_[a], xi_[b], aU[a][b]);
                aV[a][b] = fmaf(qi_[a], xr_[b], aV[a][b]);
                aV[a][b] = fmaf(-qr_[a], xi_[b], aV[a][b]);
            }
    }
    float* base = part + (size_t)bid * 16384;
    const int k0 = kt * 4, c0 = ctA * 4;
#pragma unroll
    for (int a = 0; a < 4; ++a) {
        *(float4*)(base + (k0 + a) * CC + c0)        = make_float4(aU[a][0], aU[a][1], aU[a][2], aU[a][3]);
        *(float4*)(base + 8192 + (k0 + a) * CC + c0) = make_float4(aV[a][0], aV[a][1], aV[a][2], aV[a][3]);
    }
}

// ---------------- kR1: reduce 625 partials -> row (pure streaming reduce) ----------------
// 256 blocks x 512 threads; block owns 16 f4 outputs; 32 partial-groups/thread-col
__global__ __launch_bounds__(512) void kR1(const float* __restrict__ part,
                                           float* __restrict__ row)
{
    __shared__ float4 red4[512];
    const int t = threadIdx.x;
    const int i = t & 15;          // output f4 within block's 16
    const int g = t >> 4;          // 0..31 partial group
    const int o = blockIdx.x * 16 + i;   // f4 output index [0,4096)
    const float4* p = (const float4*)part + (size_t)g * PART_F4 + o;
    const float4 z = make_float4(0.f, 0.f, 0.f, 0.f);
    float4 s0 = z, s1 = z, s2 = z, s3 = z;
    int pp = g;
    for (; pp + 96 < NCH; pp += 128) {   // 4 independent chains
        s0 = f4add(s0, p[0]);
        s1 = f4add(s1, p[(size_t)32 * PART_F4]);
        s2 = f4add(s2, p[(size_t)64 * PART_F4]);
        s3 = f4add(s3, p[(size_t)96 * PART_F4]);
        p += (size_t)128 * PART_F4;
    }
    for (; pp < NCH; pp += 32) {
        s0 = f4add(s0, p[0]);
        p += (size_t)32 * PART_F4;
    }
    red4[t] = f4add(f4add(s0, s1), f4add(s2, s3));
    __syncthreads();
    if (t < 16) {
        float4 tot = z;
#pragma unroll
        for (int gg = 0; gg < 32; ++gg) tot = f4add(tot, red4[gg * 16 + t]);
        ((float4*)row)[blockIdx.x * 16 + t] = tot;
    }
}

// ---------------- kR2: UVW = TT * (row @ W) ----------------
// 128 blocks = (m,k); 128 threads = c
__global__ __launch_bounds__(128) void kR2(const float* __restrict__ row,
                                           const float* __restrict__ Ritz,
                                           const int* __restrict__ ldp,
                                           const float* __restrict__ W,
                                           float* __restrict__ UVW)
{
    __shared__ float rowS[128];
    const int t = threadIdx.x;
    const int m = blockIdx.x >> 6, k = blockIdx.x & 63;
    rowS[t] = row[m * 8192 + k * 128 + t];
    __syncthreads();
    float acc = 0.f;
#pragma unroll 8
    for (int cp = 0; cp < 128; ++cp)
        acc = fmaf(rowS[cp], W[cp * 128 + t], acc);
    const int ld = *ldp;
    const float rz = Ritz[k];
    float tt = 1.f;
    for (int i = 0; i < ld; ++i) tt *= rz;
    UVW[m * 8192 + k * 128 + t] = tt * acc;
}

// ---------------- kC: res = Q @ UVW + masked-ReLU epilogue ----------------
// 625 blocks x 256 threads, 16 rows/block, thread = 2 rows x 4 cols.
// No LDS: UVW (64 KB) stays L1/L2-hot, read directly -> no occupancy cap, no barrier.
__global__ __launch_bounds__(256) void kC(const float* __restrict__ re,
                                          const float* __restrict__ im,
                                          const float* __restrict__ Qr,
                                          const float* __restrict__ Qi,
                                          const float* __restrict__ UVW,
                                          float* __restrict__ out)
{
    const int t = threadIdx.x;
    const int ct = t & 31;   // float4 col group: cols 4*ct..+3
    const int r  = t >> 5;   // 0..7
    const int na = blockIdx.x * 16 + r;      // rows na and na+8
    const int nb = na + 8;
    const float4* U4 = (const float4*)UVW;   // [64][32] f4
    const float4* V4 = U4 + 2048;

    const float4* qra = (const float4*)(Qr + (size_t)na * KK);
    const float4* qia = (const float4*)(Qi + (size_t)na * KK);
    const float4* qrb = (const float4*)(Qr + (size_t)nb * KK);
    const float4* qib = (const float4*)(Qi + (size_t)nb * KK);

    float4 z = make_float4(0.f, 0.f, 0.f, 0.f);
    float4 Ra = z, Ia = z, Rb = z, Ib = z;

#pragma unroll 4
    for (int k4 = 0; k4 < 16; ++k4) {
        float4 QRa = qra[k4], QIa = qia[k4];
        float4 QRb = qrb[k4], QIb = qib[k4];
        float ar[4] = {QRa.x, QRa.y, QRa.z, QRa.w};
        float ai[4] = {QIa.x, QIa.y, QIa.z, QIa.w};
        float br[4] = {QRb.x, QRb.y, QRb.z, QRb.w};
        float bi[4] = {QIb.x, QIb.y, QIb.z, QIb.w};
#pragma unroll
        for (int jj = 0; jj < 4; ++jj) {
            const int k = k4 * 4 + jj;
            float4 uw = U4[k * 32 + ct];
            float4 vw = V4[k * 32 + ct];
            Ra = f4fma(ar[jj], uw, Ra); Ra = f4fma(ai[jj], vw, Ra);
            Ia = f4fma(ai[jj], uw, Ia); Ia = f4fma(-ar[jj], vw, Ia);
            Rb = f4fma(br[jj], uw, Rb); Rb = f4fma(bi[jj], vw, Rb);
            Ib = f4fma(bi[jj], uw, Ib); Ib = f4fma(-br[jj], vw, Ib);
        }
    }
    const int cc = ct * 4;
    {
        float4 rin = *(const float4*)(re + (size_t)na * CC + cc);
        float4 iin = *(const float4*)(im + (size_t)na * CC + cc);
        float4 orr, oii;
        orr.x = rin.x + (Ra.x >= 0.f ? Ra.x : 0.f); oii.x = iin.x + (Ra.x >= 0.f ? Ia.x : 0.f);
        orr.y = rin.y + (Ra.y >= 0.f ? Ra.y : 0.f); oii.y = iin.y + (Ra.y >= 0.f ? Ia.y : 0.f);
        orr.z = rin.z + (Ra.z >= 0.f ? Ra.z : 0.f); oii.z = iin.z + (Ra.z >= 0.f ? Ia.z : 0.f);
        orr.w = rin.w + (Ra.w >= 0.f ? Ra.w : 0.f); oii.w = iin.w + (Ra.w >= 0.f ? Ia.w : 0.f);
        *(float4*)(out + (size_t)na * CC + cc)          = orr;
        *(float4*)(out + OUTOFF + (size_t)na * CC + cc) = oii;
    }
    {
        float4 rin = *(const float4*)(re + (size_t)nb * CC + cc);
        float4 iin = *(const float4*)(im + (size_t)nb * CC + cc);
        float4 orr, oii;
        orr.x = rin.x + (Rb.x >= 0.f ? Rb.x : 0.f); oii.x = iin.x + (Rb.x >= 0.f ? Ib.x : 0.f);
        orr.y = rin.y + (Rb.y >= 0.f ? Rb.y : 0.f); oii.y = iin.y + (Rb.y >= 0.f ? Ib.y : 0.f);
        orr.z = rin.z + (Rb.z >= 0.f ? Rb.z : 0.f); oii.z = iin.z + (Rb.z >= 0.f ? Ib.z : 0.f);
        orr.w = rin.w + (Rb.w >= 0.f ? Rb.w : 0.f); oii.w = iin.w + (Rb.w >= 0.f ? Ib.w : 0.f);
        *(float4*)(out + (size_t)nb * CC + cc)          = orr;
        *(float4*)(out + OUTOFF + (size_t)nb * CC + cc) = oii;
    }
}

extern "C" void kernel_launch(void* const* d_in, const int* in_sizes, int n_in,
                              void* d_out, int out_size, void* d_ws, size_t ws_size,
                              hipStream_t stream) {
    const float* re   = (const float*)d_in[0];
    const float* im   = (const float*)d_in[1];
    const float* Qr   = (const float*)d_in[2];
    const float* Qi   = (const float*)d_in[3];
    const float* Ritz = (const float*)d_in[4];
    const float* W    = (const float*)d_in[5];
    const int*   ldp  = (const int*)d_in[6];
    float* out = (float*)d_out;
    float* ws  = (float*)d_ws;

    float* part = ws;                                   // 625 * 16384 floats (41 MB)
    float* row  = ws + (size_t)NCH * 16384;             // 16384 floats
    float* UVW  = row + 16384;                          // 16384 floats

    kA <<<NCH, 512, 0, stream>>>(re, im, Qr, Qi, part);
    kR1<<<256, 512, 0, stream>>>(part, row);
    kR2<<<128, 128, 0, stream>>>(row, Ritz, ldp, W, UVW);
    kC <<<NCH, 256, 0, stream>>>(re, im, Qr, Qi, UVW, out);
}